// Round 1
// baseline (172.440 us; speedup 1.0000x reference)
//
#include <hip/hip_runtime.h>
#include <math.h>

#define T_DIM 2048
#define C_DIM 1024
#define H_DIM 64
#define M_TOTAL 16384            // B*T
#define NQKV 192                 // k(0..63) | q(64..127) | v(128..191)

typedef __bf16 bf16x8 __attribute__((ext_vector_type(8)));
typedef float f32x4 __attribute__((ext_vector_type(4)));
typedef float f32x2 __attribute__((ext_vector_type(2)));
typedef unsigned short u16x8 __attribute__((ext_vector_type(8)));

#if __has_builtin(__builtin_amdgcn_fdot2_f32_bf16)
#define HAVE_DOT2 1
typedef __bf16 bf16x2 __attribute__((ext_vector_type(2)));
#else
#define HAVE_DOT2 0
#endif

__device__ __forceinline__ unsigned short f2bf(float f) {
    unsigned u = __float_as_uint(f);
    unsigned r = (u + 0x7FFFu + ((u >> 16) & 1u)) >> 16;   // RNE
    return (unsigned short)r;
}
__device__ __forceinline__ float bf2f(unsigned short u) {
    return __uint_as_float(((unsigned)u) << 16);
}
__device__ __forceinline__ float blo(unsigned u) { return __uint_as_float(u << 16); }
__device__ __forceinline__ float bhi(unsigned u) { return __uint_as_float(u & 0xFFFF0000u); }
__device__ __forceinline__ unsigned pack_bf2(float f0, float f1) {
    unsigned u0 = __float_as_uint(f0) + 0x8000u;
    unsigned u1 = __float_as_uint(f1) + 0x8000u;
    return __builtin_amdgcn_perm(u1, u0, 0x07060302u);
}
__device__ __forceinline__ uint4 cvt8(float4 a, float4 b) {
    return make_uint4(pack_bf2(a.x, a.y), pack_bf2(a.z, a.w),
                      pack_bf2(b.x, b.y), pack_bf2(b.z, b.w));
}

// 8-elem bf16 dot: v_dot2_f32_bf16 when available, fma fallback.
__device__ __forceinline__ float dot8bf(u16x8 a, u16x8 b, float c) {
#if HAVE_DOT2
    bf16x8 av = __builtin_bit_cast(bf16x8, a);
    bf16x8 bv = __builtin_bit_cast(bf16x8, b);
    #pragma unroll
    for (int e = 0; e < 4; ++e) {
        bf16x2 ap = {av[2 * e], av[2 * e + 1]};
        bf16x2 bp = {bv[2 * e], bv[2 * e + 1]};
        c = __builtin_amdgcn_fdot2_f32_bf16(ap, bp, c, false);
    }
#else
    #pragma unroll
    for (int e = 0; e < 8; ++e) c = fmaf(bf2f(a[e]), bf2f(b[e]), c);
#endif
    return c;
}

// ---------------------------------------------------------------------------
// DPP cross-lane (VALU pipe, replaces ds_swizzle-based __shfl_xor).
// 0xB1 = quad_perm(1,0,3,2) -> true xor1
// 0x4E = quad_perm(2,3,0,1) -> true xor2
// 0x141 = row_half_mirror (l^7 within 8) == xor4 once 4-groups are duplicated
// 0x140 = row_mirror      (l^15 within 16) == xor8 once 8-groups are duplicated
// ---------------------------------------------------------------------------
#if __has_builtin(__builtin_amdgcn_update_dpp)
#define HAVE_DPP 1
template<int CTRL>
__device__ __forceinline__ float dppf(float x) {
    int v = __builtin_amdgcn_update_dpp(0, __builtin_bit_cast(int, x),
                                        CTRL, 0xF, 0xF, true);
    return __builtin_bit_cast(float, v);
}
__device__ __forceinline__ float red8(float p) {          // sum over 8-lane group
    p += dppf<0xB1>(p);
    p += dppf<0x4E>(p);
    p += dppf<0x141>(p);
    return p;
}
__device__ __forceinline__ float redsum16(float p) {      // sum over 16-lane row
    p += dppf<0xB1>(p);
    p += dppf<0x4E>(p);
    p += dppf<0x141>(p);
    p += dppf<0x140>(p);
    return p;
}
__device__ __forceinline__ float redmax16(float p) {
    p = fmaxf(p, dppf<0xB1>(p));
    p = fmaxf(p, dppf<0x4E>(p));
    p = fmaxf(p, dppf<0x141>(p));
    p = fmaxf(p, dppf<0x140>(p));
    return p;
}
#else
#define HAVE_DPP 0
__device__ __forceinline__ float red8(float p) {
    p += __shfl_xor(p, 1); p += __shfl_xor(p, 2); p += __shfl_xor(p, 4);
    return p;
}
__device__ __forceinline__ float redsum16(float p) {
    p += __shfl_xor(p, 1); p += __shfl_xor(p, 2);
    p += __shfl_xor(p, 4); p += __shfl_xor(p, 8);
    return p;
}
__device__ __forceinline__ float redmax16(float p) {
    p = fmaxf(p, __shfl_xor(p, 1)); p = fmaxf(p, __shfl_xor(p, 2));
    p = fmaxf(p, __shfl_xor(p, 4)); p = fmaxf(p, __shfl_xor(p, 8));
    return p;
}
#endif

// ---------------------------------------------------------------------------
// Kernel 0: per-row random dedup + compaction, shared by all 8 batches.
// rjc[i][0..nval) = valid deduped random cols, pads = 0; nvalb[i] = count.
// ---------------------------------------------------------------------------
__global__ __launch_bounds__(256) void compact_kernel(
    const int* __restrict__ rnd,          // [2048][64]
    int* __restrict__ rjc,                // [2048][64]
    int* __restrict__ nvalb)              // [2048]
{
    __shared__ unsigned bm_all[4][64];
    const int wv = threadIdx.x >> 6;
    const int ln = threadIdx.x & 63;
    const int i  = blockIdx.x * 4 + wv;
    unsigned* bm = bm_all[wv];

    bm[ln] = 0u;
    int  j2 = rnd[i * 64 + ln];
    bool v2 = (j2 < i - 63) && (j2 >= 64);
    if (v2) {   // dedup: winner of atomicOr keeps the column
        unsigned old = atomicOr(&bm[j2 >> 5], 1u << (j2 & 31));
        v2 = ((old >> (j2 & 31)) & 1u) == 0u;
    }
    unsigned long long mbal = __ballot(v2);
    const int nval = __popcll(mbal);
    if (v2) {
        int pos = __popcll(mbal & ((1ull << ln) - 1ull));
        rjc[i * 64 + pos] = j2;
    }
    if (ln >= nval) rjc[i * 64 + ln] = 0;   // safe pad (disjoint addresses)
    if (ln == 0) nvalb[i] = nval;
}

// ---------------------------------------------------------------------------
// Kernel 1: fused convert + bf16 MFMA QKV projection (unchanged).
// ---------------------------------------------------------------------------
__global__ __launch_bounds__(512) void proj_kernel(
    const float* __restrict__ x,
    const float* __restrict__ Wk,
    const float* __restrict__ Wq,
    const float* __restrict__ Wv,
    unsigned short* __restrict__ qkv)   // [16384][192] bf16 bits
{
    __shared__ unsigned short Ab[64 * 64];    // [row][k^swz]
    __shared__ unsigned short Bb[192 * 64];   // [col][k^swz]

    const int m0 = blockIdx.x * 64;
    const int t  = threadIdx.x;
    const int wv = t >> 6, ln = t & 63;
    const int mfr = ln & 15, kq = ln >> 4;
    const int r0 = (wv & 1) * 32;
    const int c0 = (wv >> 1) * 48;

    const int srow  = t >> 3;                // 0..63
    const int sk8   = (t & 7) * 8;
    const int skoff = sk8 ^ ((srow & 7) * 8);

    const float* gp[4] = {
        x  + (size_t)(m0 + srow) * C_DIM + sk8,
        Wk + (size_t)srow * C_DIM + sk8,
        Wq + (size_t)srow * C_DIM + sk8,
        Wv + (size_t)srow * C_DIM + sk8 };
    unsigned short* lp[4] = {
        &Ab[srow * 64 + skoff],
        &Bb[srow * 64 + skoff],
        &Bb[(srow + 64) * 64 + skoff],
        &Bb[(srow + 128) * 64 + skoff] };

    f32x4 acc[2][3] = {};

    float4 ra[4], rb[4];
    #pragma unroll
    for (int s = 0; s < 4; ++s) {
        ra[s] = *(const float4*)(gp[s]);
        rb[s] = *(const float4*)(gp[s] + 4);
    }

    for (int kc = 0; kc < C_DIM; kc += 64) {
        __syncthreads();
        #pragma unroll
        for (int s = 0; s < 4; ++s)
            *(uint4*)lp[s] = cvt8(ra[s], rb[s]);
        if (kc + 64 < C_DIM) {
            #pragma unroll
            for (int s = 0; s < 4; ++s) {
                ra[s] = *(const float4*)(gp[s] + kc + 64);
                rb[s] = *(const float4*)(gp[s] + kc + 68);
            }
        }
        __syncthreads();
        #pragma unroll
        for (int ks = 0; ks < 64; ks += 32) {
            bf16x8 af[2], bf[3];
            #pragma unroll
            for (int a = 0; a < 2; ++a) {
                int row = r0 + a * 16 + mfr;
                af[a] = *(const bf16x8*)&Ab[row * 64 + ((ks + kq * 8) ^ ((row & 7) * 8))];
            }
            #pragma unroll
            for (int b2 = 0; b2 < 3; ++b2) {
                int row = c0 + b2 * 16 + mfr;
                bf[b2] = *(const bf16x8*)&Bb[row * 64 + ((ks + kq * 8) ^ ((row & 7) * 8))];
            }
            #pragma unroll
            for (int a = 0; a < 2; ++a)
                #pragma unroll
                for (int b2 = 0; b2 < 3; ++b2)
                    acc[a][b2] = __builtin_amdgcn_mfma_f32_16x16x32_bf16(
                        af[a], bf[b2], acc[a][b2], 0, 0, 0);
        }
    }

    #pragma unroll
    for (int a = 0; a < 2; ++a)
        #pragma unroll
        for (int b2 = 0; b2 < 3; ++b2)
            #pragma unroll
            for (int r = 0; r < 4; ++r) {
                int row = m0 + r0 + a * 16 + kq * 4 + r;
                int col = c0 + b2 * 16 + mfr;
                qkv[(size_t)row * NQKV + col] = f2bf(acc[a][b2][r]);
            }
}

// ---------------------------------------------------------------------------
// Kernel 2: sparse BigBird attention — R10: DS-pipe diet.
// One wave per query, barrier-free, XCD swizzle. All intra-wave reductions
// moved to VALU DPP; PV re-laid out with row-group in the LOW 3 lane bits so
// its cross-group reduce is xor1/2/4 (pure DPP) and its weight/index reads
// are contiguous b128 vectors. Random dedup hoisted to compact_kernel.
// Slot map unchanged: s in [0,64): local col max(i-s,0); [64,128): global
// col s-64; [128,192): compacted random rjc[i][s-128], valid iff s-128<nval.
// ---------------------------------------------------------------------------
__global__ __launch_bounds__(256) void attn_kernel(
    const unsigned short* __restrict__ qkv,   // bf16 bits [16384][192]
    const int*  __restrict__ rjc,             // [2048][64] compacted randoms
    const int*  __restrict__ nvalb,           // [2048]
    float* __restrict__ out)                  // [16384][64]
{
    const int wv = threadIdx.x >> 6;
    const int ln = threadIdx.x & 63;
    const int b  = blockIdx.x & 7;                  // XCD-locality swizzle
    const int i  = ((blockIdx.x >> 3) << 2) + wv;   // 0..2047
    const int bi = b * T_DIM + i;

    __shared__ float wt_all[4][192];
    float* wt = wt_all[wv];

    const int  nval = nvalb[i];                     // wave-uniform
    const int* rji  = rjc + i * 64;

    const bool v0 = (ln <= i);                      // local slot ln -> col i-ln
    const bool v1 = (ln < i - 63);                  // global col ln

    // ---- QK layout: gg = ln>>3 row-group, 8 lanes per row, e8q h-slice ----
    const int e8q = (ln & 7) * 8;
    const int gg  = ln >> 3;
    const int lq  = ln & 7;
    u16x8 qraw = *(const u16x8*)(qkv + (size_t)bi * NQKV + 64 + e8q);
    const unsigned short* kb = qkv + (size_t)b * T_DIM * NQKV;

    // ---- QK locals+globals: 16 slots/lane in 4-wide batches ----
    #pragma unroll
    for (int n = 0; n < 16; n += 4) {
        int jj[4];
        #pragma unroll
        for (int u = 0; u < 4; ++u) {
            int s = (n + u) * 8 + gg;
            int j;
            if (s < 64) { j = i - s; j = (j < 0) ? 0 : j; }
            else        { j = s - 64; }
            jj[u] = j;
        }
        u16x8 kv[4];
        #pragma unroll
        for (int u = 0; u < 4; ++u)
            kv[u] = *(const u16x8*)(kb + (size_t)jj[u] * NQKV + e8q);
        float p[4];
        #pragma unroll
        for (int u = 0; u < 4; ++u)
            p[u] = red8(dot8bf(kv[u], qraw, 0.f));
        // one vector write, 32 active lanes, 32 consecutive words (no conflict)
        float pw = (lq & 2) ? ((lq & 1) ? p[3] : p[2])
                            : ((lq & 1) ? p[1] : p[0]);
        if (lq < 4) wt[(n + lq) * 8 + gg] = pw;
    }

    // ---- QK randoms: compacted, wave-uniform guarded ----
    auto qk_rand = [&](int n0) {   // n0 in {16,20}: random idx (n0-16)*8 .. +31
        int jj[4];
        #pragma unroll
        for (int u = 0; u < 4; ++u) jj[u] = rji[(n0 - 16 + u) * 8 + gg];
        u16x8 kv[4];
        #pragma unroll
        for (int u = 0; u < 4; ++u)
            kv[u] = *(const u16x8*)(kb + (size_t)jj[u] * NQKV + e8q);
        float p[4];
        #pragma unroll
        for (int u = 0; u < 4; ++u)
            p[u] = red8(dot8bf(kv[u], qraw, 0.f));
        float pw = (lq & 2) ? ((lq & 1) ? p[3] : p[2])
                            : ((lq & 1) ? p[1] : p[0]);
        if (lq < 4) wt[(n0 + lq) * 8 + gg] = pw;
    };
    if (nval > 0)  qk_rand(16);
    if (nval > 32) qk_rand(20);

    // ---- softmax: lane handles slots {ln, 64+ln, 128+ln} ----
    const bool vs2 = (ln < nval);
    float s0 = wt[ln];
    float s1 = wt[64 + ln];
    float s2 = vs2 ? wt[128 + ln] : 0.f;
    s0 = v0  ? s0 * 0.125f : -1e30f;
    s1 = v1  ? s1 * 0.125f : -1e30f;
    s2 = vs2 ? s2 * 0.125f : -1e30f;

    float mx = fmaxf(s0, fmaxf(s1, s2));
    mx = redmax16(mx);
    mx = fmaxf(mx, __shfl_xor(mx, 16));
    mx = fmaxf(mx, __shfl_xor(mx, 32));
    float e0 = v0  ? __expf(s0 - mx) : 0.f;
    float e1 = v1  ? __expf(s1 - mx) : 0.f;
    float e2 = vs2 ? __expf(s2 - mx) : 0.f;
    float sum = e0 + e1 + e2;
    sum = redsum16(sum);
    sum += __shfl_xor(sum, 16);
    sum += __shfl_xor(sum, 32);

    wt[ln]       = e0;
    wt[64 + ln]  = e1;
    wt[128 + ln] = e2;     // pads get 0 -> executed rand batches are safe

    // ---- PV layout: row-group gp = ln&7 (LOW bits) so final reduce is DPP;
    //      weights/indices contiguous per lane -> b128 reads ----
    const int gp  = ln & 7;
    const int ee8 = (ln >> 3) * 8;
    const unsigned short* vb = kb + 128;
    f32x2 acc2[4] = {};

    #pragma unroll
    for (int bt = 0; bt < 4; ++bt) {
        f32x4 w4 = *(const f32x4*)&wt[bt * 32 + gp * 4];
        int jc[4];
        #pragma unroll
        for (int c = 0; c < 4; ++c) {
            int s = bt * 32 + gp * 4 + c;
            int j;
            if (s < 64) { j = i - s; j = (j < 0) ? 0 : j; }
            else        { j = s - 64; }
            jc[c] = j;
        }
        uint4 vv[4];
        #pragma unroll
        for (int c = 0; c < 4; ++c)
            vv[c] = *(const uint4*)(vb + (size_t)jc[c] * NQKV + ee8);
        #pragma unroll
        for (int c = 0; c < 4; ++c) {
            f32x2 w2 = {w4[c], w4[c]};
            f32x2 p0 = {blo(vv[c].x), bhi(vv[c].x)};
            f32x2 p1 = {blo(vv[c].y), bhi(vv[c].y)};
            f32x2 p2 = {blo(vv[c].z), bhi(vv[c].z)};
            f32x2 p3 = {blo(vv[c].w), bhi(vv[c].w)};
            acc2[0] += w2 * p0;
            acc2[1] += w2 * p1;
            acc2[2] += w2 * p2;
            acc2[3] += w2 * p3;
        }
    }

    // ---- PV randoms: contiguous compacted indices + weights, guarded ----
    auto pv_rand = [&](int r0) {   // r0 in {0,32}: random idx r0 .. r0+31
        int4  j4 = *(const int4*)&rji[r0 + gp * 4];
        f32x4 w4 = *(const f32x4*)&wt[128 + r0 + gp * 4];
        int jc[4] = { j4.x, j4.y, j4.z, j4.w };
        uint4 vv[4];
        #pragma unroll
        for (int c = 0; c < 4; ++c)
            vv[c] = *(const uint4*)(vb + (size_t)jc[c] * NQKV + ee8);
        #pragma unroll
        for (int c = 0; c < 4; ++c) {
            f32x2 w2 = {w4[c], w4[c]};
            f32x2 p0 = {blo(vv[c].x), bhi(vv[c].x)};
            f32x2 p1 = {blo(vv[c].y), bhi(vv[c].y)};
            f32x2 p2 = {blo(vv[c].z), bhi(vv[c].z)};
            f32x2 p3 = {blo(vv[c].w), bhi(vv[c].w)};
            acc2[0] += w2 * p0;
            acc2[1] += w2 * p1;
            acc2[2] += w2 * p2;
            acc2[3] += w2 * p3;
        }
    };
    if (nval > 0)  pv_rand(0);
    if (nval > 32) pv_rand(32);

    float acc[8] = { acc2[0][0], acc2[0][1], acc2[1][0], acc2[1][1],
                     acc2[2][0], acc2[2][1], acc2[3][0], acc2[3][1] };
    // reduce across the 8 row-groups (low 3 lane bits -> pure DPP)
#if HAVE_DPP
    #pragma unroll
    for (int e = 0; e < 8; ++e) {
        acc[e] += dppf<0xB1>(acc[e]);
        acc[e] += dppf<0x4E>(acc[e]);
        acc[e] += dppf<0x141>(acc[e]);
    }
#else
    #pragma unroll
    for (int m = 1; m <= 4; m <<= 1)
        #pragma unroll
        for (int e = 0; e < 8; ++e)
            acc[e] += __shfl_xor(acc[e], m);
#endif

    if (gp == 0) {
        float inv = 1.f / sum;
        float* op = &out[(size_t)bi * H_DIM + ee8];
        *(float4*)op       = make_float4(acc[0]*inv, acc[1]*inv, acc[2]*inv, acc[3]*inv);
        *(float4*)(op + 4) = make_float4(acc[4]*inv, acc[5]*inv, acc[6]*inv, acc[7]*inv);
    }
}

// ---------------------------------------------------------------------------
extern "C" void kernel_launch(void* const* d_in, const int* in_sizes, int n_in,
                              void* d_out, int out_size, void* d_ws, size_t ws_size,
                              hipStream_t stream) {
    const float* x   = (const float*)d_in[0];
    const int*   rnd = (const int*)  d_in[1];
    const float* Wk  = (const float*)d_in[2];
    const float* Wq  = (const float*)d_in[3];
    const float* Wv  = (const float*)d_in[4];
    float* out = (float*)d_out;

    unsigned short* qkv = (unsigned short*)d_ws;             // 6,291,456 B
    int* rjc   = (int*)((char*)d_ws + 6291456);              // 524,288 B
    int* nvalb = rjc + T_DIM * 64;                           // 8,192 B

    compact_kernel<<<T_DIM / 4, 256, 0, stream>>>(rnd, rjc, nvalb);
    proj_kernel<<<M_TOTAL / 64, 512, 0, stream>>>(x, Wk, Wq, Wv, qkv);
    attn_kernel<<<M_TOTAL / 4, 256, 0, stream>>>(qkv, rjc, nvalb, out);
}

// Round 3
// 149.250 us; speedup vs baseline: 1.1554x; 1.1554x over previous
//
#include <hip/hip_runtime.h>
#include <math.h>

#define T_DIM 2048
#define C_DIM 1024
#define H_DIM 64
#define M_TOTAL 16384            // B*T
#define NQKV 192                 // k(0..63) | q(64..127) | v(128..191)

typedef __bf16 bf16x8 __attribute__((ext_vector_type(8)));
typedef float f32x4 __attribute__((ext_vector_type(4)));
typedef float f32x2 __attribute__((ext_vector_type(2)));
typedef unsigned short u16x8 __attribute__((ext_vector_type(8)));

#if __has_builtin(__builtin_amdgcn_fdot2_f32_bf16)
#define HAVE_DOT2 1
typedef __bf16 bf16x2 __attribute__((ext_vector_type(2)));
#else
#define HAVE_DOT2 0
#endif

__device__ __forceinline__ unsigned short f2bf(float f) {
    unsigned u = __float_as_uint(f);
    unsigned r = (u + 0x7FFFu + ((u >> 16) & 1u)) >> 16;   // RNE
    return (unsigned short)r;
}
__device__ __forceinline__ float bf2f(unsigned short u) {
    return __uint_as_float(((unsigned)u) << 16);
}
__device__ __forceinline__ float blo(unsigned u) { return __uint_as_float(u << 16); }
__device__ __forceinline__ float bhi(unsigned u) { return __uint_as_float(u & 0xFFFF0000u); }
__device__ __forceinline__ unsigned pack_bf2(float f0, float f1) {
    unsigned u0 = __float_as_uint(f0) + 0x8000u;
    unsigned u1 = __float_as_uint(f1) + 0x8000u;
    return __builtin_amdgcn_perm(u1, u0, 0x07060302u);
}
__device__ __forceinline__ uint4 cvt8(float4 a, float4 b) {
    return make_uint4(pack_bf2(a.x, a.y), pack_bf2(a.z, a.w),
                      pack_bf2(b.x, b.y), pack_bf2(b.z, b.w));
}

// 8-elem bf16 dot: v_dot2_f32_bf16 when available, fma fallback.
__device__ __forceinline__ float dot8bf(u16x8 a, u16x8 b, float c) {
#if HAVE_DOT2
    bf16x8 av = __builtin_bit_cast(bf16x8, a);
    bf16x8 bv = __builtin_bit_cast(bf16x8, b);
    #pragma unroll
    for (int e = 0; e < 4; ++e) {
        bf16x2 ap = {av[2 * e], av[2 * e + 1]};
        bf16x2 bp = {bv[2 * e], bv[2 * e + 1]};
        c = __builtin_amdgcn_fdot2_f32_bf16(ap, bp, c, false);
    }
#else
    #pragma unroll
    for (int e = 0; e < 8; ++e) c = fmaf(bf2f(a[e]), bf2f(b[e]), c);
#endif
    return c;
}

// ---------------------------------------------------------------------------
// DPP cross-lane (VALU pipe). 0xB1=xor1, 0x4E=xor2, 0x141=row_half_mirror
// (==xor4 on 4-uniform data), 0x140=row_mirror (==xor8 on 8-uniform data).
// Validated end-to-end by the R10 passing run.
// ---------------------------------------------------------------------------
#if __has_builtin(__builtin_amdgcn_update_dpp)
#define HAVE_DPP 1
template<int CTRL>
__device__ __forceinline__ float dppf(float x) {
    int v = __builtin_amdgcn_update_dpp(0, __builtin_bit_cast(int, x),
                                        CTRL, 0xF, 0xF, true);
    return __builtin_bit_cast(float, v);
}
__device__ __forceinline__ float red8(float p) {          // sum over 8-lane group
    p += dppf<0xB1>(p);
    p += dppf<0x4E>(p);
    p += dppf<0x141>(p);
    return p;
}
__device__ __forceinline__ float redsum16(float p) {      // sum over 16-lane row
    p += dppf<0xB1>(p);
    p += dppf<0x4E>(p);
    p += dppf<0x141>(p);
    p += dppf<0x140>(p);
    return p;
}
__device__ __forceinline__ float redmax16(float p) {
    p = fmaxf(p, dppf<0xB1>(p));
    p = fmaxf(p, dppf<0x4E>(p));
    p = fmaxf(p, dppf<0x141>(p));
    p = fmaxf(p, dppf<0x140>(p));
    return p;
}
#else
#define HAVE_DPP 0
__device__ __forceinline__ float red8(float p) {
    p += __shfl_xor(p, 1); p += __shfl_xor(p, 2); p += __shfl_xor(p, 4);
    return p;
}
__device__ __forceinline__ float redsum16(float p) {
    p += __shfl_xor(p, 1); p += __shfl_xor(p, 2);
    p += __shfl_xor(p, 4); p += __shfl_xor(p, 8);
    return p;
}
__device__ __forceinline__ float redmax16(float p) {
    p = fmaxf(p, __shfl_xor(p, 1)); p = fmaxf(p, __shfl_xor(p, 2));
    p = fmaxf(p, __shfl_xor(p, 4)); p = fmaxf(p, __shfl_xor(p, 8));
    return p;
}
#endif

// ---------------------------------------------------------------------------
// Kernel 0: per-row random dedup + compaction (R10-validated, unchanged).
// ---------------------------------------------------------------------------
__global__ __launch_bounds__(256) void compact_kernel(
    const int* __restrict__ rnd,          // [2048][64]
    int* __restrict__ rjc,                // [2048][64]
    int* __restrict__ nvalb)              // [2048]
{
    __shared__ unsigned bm_all[4][64];
    const int wv = threadIdx.x >> 6;
    const int ln = threadIdx.x & 63;
    const int i  = blockIdx.x * 4 + wv;
    unsigned* bm = bm_all[wv];

    bm[ln] = 0u;
    int  j2 = rnd[i * 64 + ln];
    bool v2 = (j2 < i - 63) && (j2 >= 64);
    if (v2) {   // dedup: winner of atomicOr keeps the column
        unsigned old = atomicOr(&bm[j2 >> 5], 1u << (j2 & 31));
        v2 = ((old >> (j2 & 31)) & 1u) == 0u;
    }
    unsigned long long mbal = __ballot(v2);
    const int nval = __popcll(mbal);
    if (v2) {
        int pos = __popcll(mbal & ((1ull << ln) - 1ull));
        rjc[i * 64 + pos] = j2;
    }
    if (ln >= nval) rjc[i * 64 + ln] = 0;   // safe pad (disjoint addresses)
    if (ln == 0) nvalb[i] = nval;
}

// ---------------------------------------------------------------------------
// Kernel 1: fused convert + bf16 MFMA QKV projection (unchanged).
// ---------------------------------------------------------------------------
__global__ __launch_bounds__(512) void proj_kernel(
    const float* __restrict__ x,
    const float* __restrict__ Wk,
    const float* __restrict__ Wq,
    const float* __restrict__ Wv,
    unsigned short* __restrict__ qkv)   // [16384][192] bf16 bits
{
    __shared__ unsigned short Ab[64 * 64];    // [row][k^swz]
    __shared__ unsigned short Bb[192 * 64];   // [col][k^swz]

    const int m0 = blockIdx.x * 64;
    const int t  = threadIdx.x;
    const int wv = t >> 6, ln = t & 63;
    const int mfr = ln & 15, kq = ln >> 4;
    const int r0 = (wv & 1) * 32;
    const int c0 = (wv >> 1) * 48;

    const int srow  = t >> 3;                // 0..63
    const int sk8   = (t & 7) * 8;
    const int skoff = sk8 ^ ((srow & 7) * 8);

    const float* gp[4] = {
        x  + (size_t)(m0 + srow) * C_DIM + sk8,
        Wk + (size_t)srow * C_DIM + sk8,
        Wq + (size_t)srow * C_DIM + sk8,
        Wv + (size_t)srow * C_DIM + sk8 };
    unsigned short* lp[4] = {
        &Ab[srow * 64 + skoff],
        &Bb[srow * 64 + skoff],
        &Bb[(srow + 64) * 64 + skoff],
        &Bb[(srow + 128) * 64 + skoff] };

    f32x4 acc[2][3] = {};

    float4 ra[4], rb[4];
    #pragma unroll
    for (int s = 0; s < 4; ++s) {
        ra[s] = *(const float4*)(gp[s]);
        rb[s] = *(const float4*)(gp[s] + 4);
    }

    for (int kc = 0; kc < C_DIM; kc += 64) {
        __syncthreads();
        #pragma unroll
        for (int s = 0; s < 4; ++s)
            *(uint4*)lp[s] = cvt8(ra[s], rb[s]);
        if (kc + 64 < C_DIM) {
            #pragma unroll
            for (int s = 0; s < 4; ++s) {
                ra[s] = *(const float4*)(gp[s] + kc + 64);
                rb[s] = *(const float4*)(gp[s] + kc + 68);
            }
        }
        __syncthreads();
        #pragma unroll
        for (int ks = 0; ks < 64; ks += 32) {
            bf16x8 af[2], bf[3];
            #pragma unroll
            for (int a = 0; a < 2; ++a) {
                int row = r0 + a * 16 + mfr;
                af[a] = *(const bf16x8*)&Ab[row * 64 + ((ks + kq * 8) ^ ((row & 7) * 8))];
            }
            #pragma unroll
            for (int b2 = 0; b2 < 3; ++b2) {
                int row = c0 + b2 * 16 + mfr;
                bf[b2] = *(const bf16x8*)&Bb[row * 64 + ((ks + kq * 8) ^ ((row & 7) * 8))];
            }
            #pragma unroll
            for (int a = 0; a < 2; ++a)
                #pragma unroll
                for (int b2 = 0; b2 < 3; ++b2)
                    acc[a][b2] = __builtin_amdgcn_mfma_f32_16x16x32_bf16(
                        af[a], bf[b2], acc[a][b2], 0, 0, 0);
        }
    }

    #pragma unroll
    for (int a = 0; a < 2; ++a)
        #pragma unroll
        for (int b2 = 0; b2 < 3; ++b2)
            #pragma unroll
            for (int r = 0; r < 4; ++r) {
                int row = m0 + r0 + a * 16 + kq * 4 + r;
                int col = c0 + b2 * 16 + mfr;
                qkv[(size_t)row * NQKV + col] = f2bf(acc[a][b2][r]);
            }
}

// ---------------------------------------------------------------------------
// Kernel 2: sparse BigBird attention — R12: hybrid of verified pieces.
// QK + softmax + wt[s] slot layout: exactly the R10 passing form (DPP red8,
// 4-wide batches, `if (lq<4) wt[(n+lq)*8+gg]` writes, DPP softmax).
// PV + final reduce + output: exactly the R9 passing form (row-group in HIGH
// lane bits -> 8 consecutive lanes read one contiguous 128B V row; scalar
// LDS weight reads; shfl 8/16/32 reduce; ln<8 float4 stores).
// Compaction hoisted to compact_kernel (R10-validated): attn does zero dedup.
// Slot map: s in [0,64): local col max(i-s,0); [64,128): global col s-64;
// [128,192): compacted random rjc[i][s-128], valid iff s-128 < nval.
// ---------------------------------------------------------------------------
__global__ __launch_bounds__(256) void attn_kernel(
    const unsigned short* __restrict__ qkv,   // bf16 bits [16384][192]
    const int*  __restrict__ rjc,             // [2048][64] compacted randoms
    const int*  __restrict__ nvalb,           // [2048]
    float* __restrict__ out)                  // [16384][64]
{
    const int wv = threadIdx.x >> 6;
    const int ln = threadIdx.x & 63;
    const int b  = blockIdx.x & 7;                  // XCD-locality swizzle
    const int i  = ((blockIdx.x >> 3) << 2) + wv;   // 0..2047
    const int bi = b * T_DIM + i;

    __shared__ float wt_all[4][192];
    float* wt = wt_all[wv];

    const int  nval = nvalb[i];                     // wave-uniform
    const int* rji  = rjc + i * 64;

    const bool v0 = (ln <= i);                      // local slot ln -> col i-ln
    const bool v1 = (ln < i - 63);                  // global col ln

    // ---- layout: gg = ln>>3 row-group (HIGH bits of slot), 8 lanes/row ----
    const int e8 = (ln & 7) * 8;     // h-slice base for this lane
    const int gg = ln >> 3;          // row-group 0..7
    const int lq = ln & 7;
    u16x8 qraw = *(const u16x8*)(qkv + (size_t)bi * NQKV + 64 + e8);
    const unsigned short* kb = qkv + (size_t)b * T_DIM * NQKV;

    // ---- QK locals+globals: 16 slots/row-group in 4-wide batches ----
    #pragma unroll
    for (int n = 0; n < 16; n += 4) {
        int jj[4];
        #pragma unroll
        for (int u = 0; u < 4; ++u) {
            int s = (n + u) * 8 + gg;
            int j;
            if (s < 64) { j = i - s; j = (j < 0) ? 0 : j; }
            else        { j = s - 64; }
            jj[u] = j;
        }
        u16x8 kv[4];
        #pragma unroll
        for (int u = 0; u < 4; ++u)
            kv[u] = *(const u16x8*)(kb + (size_t)jj[u] * NQKV + e8);
        float p[4];
        #pragma unroll
        for (int u = 0; u < 4; ++u)
            p[u] = red8(dot8bf(kv[u], qraw, 0.f));
        // 32 active lanes, 32 distinct words (R10-validated store pattern)
        float pw = (lq & 2) ? ((lq & 1) ? p[3] : p[2])
                            : ((lq & 1) ? p[1] : p[0]);
        if (lq < 4) wt[(n + lq) * 8 + gg] = pw;
    }

    // ---- QK randoms: compacted, wave-uniform guarded ----
    auto qk_rand = [&](int n0) {   // n0 in {16,20}: random idx (n0-16)*8 .. +31
        int jj[4];
        #pragma unroll
        for (int u = 0; u < 4; ++u) jj[u] = rji[(n0 - 16 + u) * 8 + gg];
        u16x8 kv[4];
        #pragma unroll
        for (int u = 0; u < 4; ++u)
            kv[u] = *(const u16x8*)(kb + (size_t)jj[u] * NQKV + e8);
        float p[4];
        #pragma unroll
        for (int u = 0; u < 4; ++u)
            p[u] = red8(dot8bf(kv[u], qraw, 0.f));
        float pw = (lq & 2) ? ((lq & 1) ? p[3] : p[2])
                            : ((lq & 1) ? p[1] : p[0]);
        if (lq < 4) wt[(n0 + lq) * 8 + gg] = pw;
    };
    if (nval > 0)  qk_rand(16);
    if (nval > 32) qk_rand(20);

    // ---- softmax: lane handles slots {ln, 64+ln, 128+ln} (R10 form) ----
    const bool vs2 = (ln < nval);
    float s0 = wt[ln];
    float s1 = wt[64 + ln];
    float s2 = vs2 ? wt[128 + ln] : 0.f;
    s0 = v0  ? s0 * 0.125f : -1e30f;
    s1 = v1  ? s1 * 0.125f : -1e30f;
    s2 = vs2 ? s2 * 0.125f : -1e30f;

    float mx = fmaxf(s0, fmaxf(s1, s2));
    mx = redmax16(mx);
    mx = fmaxf(mx, __shfl_xor(mx, 16));
    mx = fmaxf(mx, __shfl_xor(mx, 32));
    float e0 = v0  ? __expf(s0 - mx) : 0.f;
    float e1 = v1  ? __expf(s1 - mx) : 0.f;
    float e2 = vs2 ? __expf(s2 - mx) : 0.f;
    float sum = e0 + e1 + e2;
    sum = redsum16(sum);
    sum += __shfl_xor(sum, 16);
    sum += __shfl_xor(sum, 32);

    wt[ln]       = e0;
    wt[64 + ln]  = e1;
    wt[128 + ln] = e2;     // pads get 0 -> executed rand batches are safe

    // ---- PV locals+globals: 2 fixed batches of 8 (exact R9 form) ----
    const unsigned short* vb = kb + 128;
    f32x2 acc2[4] = {};
    #pragma unroll
    for (int bt = 0; bt < 2; ++bt) {
        float w[8]; int jc[8];
        #pragma unroll
        for (int c = 0; c < 8; ++c) {
            int s = (bt * 8 + c) * 8 + gg;
            w[c] = wt[s];
            int j;
            if (s < 64) { j = i - s; j = (j < 0) ? 0 : j; }
            else        { j = s - 64; }
            jc[c] = j;
        }
        uint4 vv[8];
        #pragma unroll
        for (int c = 0; c < 8; ++c)
            vv[c] = *(const uint4*)(vb + (size_t)jc[c] * NQKV + e8);
        #pragma unroll
        for (int c = 0; c < 8; ++c) {
            f32x2 w2 = {w[c], w[c]};
            f32x2 p0 = {blo(vv[c].x), bhi(vv[c].x)};
            f32x2 p1 = {blo(vv[c].y), bhi(vv[c].y)};
            f32x2 p2 = {blo(vv[c].z), bhi(vv[c].z)};
            f32x2 p3 = {blo(vv[c].w), bhi(vv[c].w)};
            acc2[0] += w2 * p0;
            acc2[1] += w2 * p1;
            acc2[2] += w2 * p2;
            acc2[3] += w2 * p3;
        }
    }
    // ---- PV randoms: guarded 4-wide batches (R9 form, rji from global) ----
    auto pv_rand = [&](int c0) {   // c0 in {0, 4}; covers random idx c0*8 .. +31
        float w[4]; int jc[4];
        #pragma unroll
        for (int c = 0; c < 4; ++c) {
            int ridx = (c0 + c) * 8 + gg;
            w[c]  = wt[128 + ridx];
            jc[c] = rji[ridx];
        }
        uint4 vv[4];
        #pragma unroll
        for (int c = 0; c < 4; ++c)
            vv[c] = *(const uint4*)(vb + (size_t)jc[c] * NQKV + e8);
        #pragma unroll
        for (int c = 0; c < 4; ++c) {
            f32x2 w2 = {w[c], w[c]};
            f32x2 p0 = {blo(vv[c].x), bhi(vv[c].x)};
            f32x2 p1 = {blo(vv[c].y), bhi(vv[c].y)};
            f32x2 p2 = {blo(vv[c].z), bhi(vv[c].z)};
            f32x2 p3 = {blo(vv[c].w), bhi(vv[c].w)};
            acc2[0] += w2 * p0;
            acc2[1] += w2 * p1;
            acc2[2] += w2 * p2;
            acc2[3] += w2 * p3;
        }
    };
    if (nval > 0)  pv_rand(0);
    if (nval > 32) pv_rand(4);

    float acc[8] = { acc2[0][0], acc2[0][1], acc2[1][0], acc2[1][1],
                     acc2[2][0], acc2[2][1], acc2[3][0], acc2[3][1] };
    // reduce across the 8 row-groups (lane bits 3,4,5) — exact R9 form
    #pragma unroll
    for (int m = 8; m <= 32; m <<= 1)
        #pragma unroll
        for (int e = 0; e < 8; ++e)
            acc[e] += __shfl_xor(acc[e], m);

    if (ln < 8) {
        float inv = 1.f / sum;
        float* op = &out[(size_t)bi * H_DIM + e8];
        *(float4*)op       = make_float4(acc[0]*inv, acc[1]*inv, acc[2]*inv, acc[3]*inv);
        *(float4*)(op + 4) = make_float4(acc[4]*inv, acc[5]*inv, acc[6]*inv, acc[7]*inv);
    }
}

// ---------------------------------------------------------------------------
extern "C" void kernel_launch(void* const* d_in, const int* in_sizes, int n_in,
                              void* d_out, int out_size, void* d_ws, size_t ws_size,
                              hipStream_t stream) {
    const float* x   = (const float*)d_in[0];
    const int*   rnd = (const int*)  d_in[1];
    const float* Wk  = (const float*)d_in[2];
    const float* Wq  = (const float*)d_in[3];
    const float* Wv  = (const float*)d_in[4];
    float* out = (float*)d_out;

    unsigned short* qkv = (unsigned short*)d_ws;             // 6,291,456 B
    int* rjc   = (int*)((char*)d_ws + 6291456);              // 524,288 B
    int* nvalb = rjc + T_DIM * 64;                           // 8,192 B

    compact_kernel<<<T_DIM / 4, 256, 0, stream>>>(rnd, rjc, nvalb);
    proj_kernel<<<M_TOTAL / 64, 512, 0, stream>>>(x, Wk, Wq, Wv, qkv);
    attn_kernel<<<M_TOTAL / 4, 256, 0, stream>>>(qkv, rjc, nvalb, out);
}